// Round 12
// baseline (247.632 us; speedup 1.0000x reference)
//
#include <hip/hip_runtime.h>
#include <hip/hip_bf16.h>
#include <math.h>

// ---------------- problem constants ----------------
#define L_SEQ 4096            // H*W
#define NB    4
#define DIMC  192
#define DIN   384             // d_inner
#define DIN2  768
#define DTRANK 12
#define DSTATE 16
#define NKX   44              // dt_rank + 2*d_state
#define G_CHUNKS 256
#define T_CHUNK  16           // L_SEQ / G_CHUNKS
#define NCH  (NB*DIN*DSTATE)  // 24576 scan channels
#define NBD  (NB*DIN)         // 1536 (b,d) channels
#define NM   (NB*L_SEQ)       // 16384 (b,l) rows
#define LDK  200              // padded LDS row (bf16 elements) for GEMM staging

typedef __attribute__((ext_vector_type(8))) short short8;     // 8 bf16 = 4 VGPRs
typedef __attribute__((ext_vector_type(4))) float floatx4;

__device__ __forceinline__ float silu_f(float v) {
    return v / (1.f + __expf(-v));
}
// softplus via hardware v_log_f32 (log1pf is a slow libm path)
__device__ __forceinline__ float softplus_f(float v) {
    return fmaxf(v, 0.f) + __logf(1.f + __expf(-fabsf(v)));
}
__device__ __forceinline__ float bf2f(unsigned short u) {
    union { unsigned int i; float f; } c; c.i = ((unsigned int)u) << 16; return c.f;
}
__device__ __forceinline__ unsigned short f2bf(float f) {
    __hip_bfloat16 h = __float2bfloat16(f);
    return *(unsigned short*)&h;
}

// ------- weights -> bf16: W_in (768x192), W_out (192x384), W_x padded (64x384) -------
#define NWI (DIN2*DIMC)        // 147456
#define NWO (DIMC*DIN)         // 73728
#define NWX (64*DIN)           // 24576 (rows 44..63 zero)
__launch_bounds__(256)
__global__ void k_cvt_w(const float* __restrict__ W_in, const float* __restrict__ W_out,
                        const float* __restrict__ W_x,
                        __hip_bfloat16* __restrict__ wbi, __hip_bfloat16* __restrict__ wbo,
                        __hip_bfloat16* __restrict__ wbx) {
    const int i = blockIdx.x * 256 + threadIdx.x;
    if (i < NWI) {
        wbi[i] = __float2bfloat16(W_in[i]);
    } else if (i < NWI + NWO) {
        const int j = i - NWI;
        wbo[j] = __float2bfloat16(W_out[j]);
    } else if (i < NWI + NWO + NWX) {
        const int j = i - NWI - NWO;
        const int r = j / DIN, c = j - r * DIN;
        wbx[j] = (r < NKX) ? __float2bfloat16(W_x[(size_t)r * DIN + c])
                           : __float2bfloat16(0.f);
    }
}

// ---------------- in_proj: xzb(m,768) bf16 = x^T(m,192) @ W_in^T ----------------
// grid (6 n-tiles, 256 m-tiles): n fast-varying for A-tile cache reuse.
__launch_bounds__(256)
__global__ void k_gemm_in(const float* __restrict__ x, const __hip_bfloat16* __restrict__ W,
                          __hip_bfloat16* __restrict__ xzb) {
    __shared__ __align__(16) __hip_bfloat16 sA[64 * LDK];
    __shared__ __align__(16) __hip_bfloat16 sB[128 * LDK];
    const int tid = threadIdx.x;
    const int lane = tid & 63;
    const int wave = tid >> 6;
    const int wm = wave >> 1, wn = wave & 1;
    const int m0 = blockIdx.y * 64;
    const int b = m0 >> 12, l0 = m0 & (L_SEQ - 1);
    const int n0 = blockIdx.x * 128;
    const int mlan = lane & 15;
    const int kq8 = (lane >> 4) * 8;

#pragma unroll
    for (int r = 0; r < 12; ++r) {
        const int idx = r * 256 + tid;
        const int c = idx >> 4, lq = (idx & 15) * 4;
        const float4 v = *(const float4*)&x[((size_t)b * DIMC + c) * L_SEQ + l0 + lq];
        sA[(lq + 0) * LDK + c] = __float2bfloat16(v.x);
        sA[(lq + 1) * LDK + c] = __float2bfloat16(v.y);
        sA[(lq + 2) * LDK + c] = __float2bfloat16(v.z);
        sA[(lq + 3) * LDK + c] = __float2bfloat16(v.w);
    }
#pragma unroll
    for (int r = 0; r < 12; ++r) {
        const int idx = r * 256 + tid;
        const int row = idx / 24, cc = idx % 24;
        const uint4 wv = *(const uint4*)&W[(size_t)(n0 + row) * DIMC + cc * 8];
        *(uint4*)&sB[row * LDK + cc * 8] = wv;
    }
    __syncthreads();

    floatx4 acc[2][4];
#pragma unroll
    for (int i = 0; i < 2; ++i)
#pragma unroll
        for (int j = 0; j < 4; ++j) acc[i][j] = (floatx4){0.f, 0.f, 0.f, 0.f};
#pragma unroll
    for (int ks = 0; ks < 6; ++ks) {
        short8 af[2], bf[4];
#pragma unroll
        for (int im = 0; im < 2; ++im)
            af[im] = *(const short8*)&sA[(wm*32 + im*16 + mlan) * LDK + ks*32 + kq8];
#pragma unroll
        for (int jn = 0; jn < 4; ++jn)
            bf[jn] = *(const short8*)&sB[(wn*64 + jn*16 + mlan) * LDK + ks*32 + kq8];
#pragma unroll
        for (int im = 0; im < 2; ++im)
#pragma unroll
            for (int jn = 0; jn < 4; ++jn)
                acc[im][jn] = __builtin_amdgcn_mfma_f32_16x16x32_bf16(
                    af[im], bf[jn], acc[im][jn], 0, 0, 0);
    }
    const int quad = lane >> 4;
#pragma unroll
    for (int im = 0; im < 2; ++im)
#pragma unroll
        for (int jn = 0; jn < 4; ++jn) {
            const int n = n0 + wn*64 + jn*16 + mlan;
            const int mb = m0 + wm*32 + im*16 + quad*4;
#pragma unroll
            for (int r = 0; r < 4; ++r)
                xzb[(size_t)(mb + r) * DIN2 + n] = __float2bfloat16(acc[im][jn][r]);
        }
}

// ------- x_proj with FUSED depthwise conv4+SiLU producer AND fused dt_proj ----------
// Per K-chunk (192): stage raw xzb rows m0-3..m0+63 -> LDS, conv+SiLU -> sA tile,
// also write sA out as xcb (bf16 m-major). MFMA vs wbx. Epilogue: xdbl(m,48) f32 +
// dlt(m,384) bf16 = softplus(xdbl[:,:12] @ Wdt^T + 2*b_dt) computed from LDS sdt.
__launch_bounds__(256)
__global__ void k_gemm_xp(const __hip_bfloat16* __restrict__ xzb,
                          const __hip_bfloat16* __restrict__ wbx,
                          const float* __restrict__ cw, const float* __restrict__ cb,
                          const float* __restrict__ Wdt, const float* __restrict__ bdt,
                          __hip_bfloat16* __restrict__ xcb, float* __restrict__ xdbl,
                          __hip_bfloat16* __restrict__ dlt) {
    __shared__ __align__(16) __hip_bfloat16 sXZ[68 * LDK];
    __shared__ __align__(16) __hip_bfloat16 sA[64 * LDK];
    __shared__ __align__(16) __hip_bfloat16 sB[64 * LDK];
    __shared__ __align__(16) float4 scw[192];
    __shared__ float scb[192];
    __shared__ float sdt[64][12];
    const int tid = threadIdx.x;
    const int lane = tid & 63;
    const int wave = tid >> 6;
    const int wm = wave >> 1, wn = wave & 1;
    const int m0 = blockIdx.x * 64;
    const int l0 = m0 & (L_SEQ - 1);
    const int mlan = lane & 15;
    const int kq8 = (lane >> 4) * 8;

    floatx4 acc[2][2];
#pragma unroll
    for (int i = 0; i < 2; ++i)
#pragma unroll
        for (int j = 0; j < 2; ++j) acc[i][j] = (floatx4){0.f, 0.f, 0.f, 0.f};

    for (int kh = 0; kh < DIN; kh += 192) {
        if (kh) __syncthreads();                     // protect sXZ/sB vs prior MFMA
        // stage raw xz: 67 rows x 192 cols (row j <-> l = l0-3+j), zero left edge
#pragma unroll
        for (int r = 0; r < 7; ++r) {
            const int idx = r * 256 + tid;
            if (idx < 67 * 24) {
                const int row = idx / 24, cc = idx % 24;
                uint4 v = {0u, 0u, 0u, 0u};
                if (l0 - 3 + row >= 0)
                    v = *(const uint4*)&xzb[(size_t)(m0 - 3 + row) * DIN2 + kh + cc * 8];
                *(uint4*)&sXZ[row * LDK + cc * 8] = v;
            }
        }
        if (tid < 192) {
            scw[tid] = *(const float4*)&cw[(kh + tid) * 4];
            scb[tid] = cb[kh + tid];
        }
        // stage B: wbx rows 0..63 of this k-chunk
#pragma unroll
        for (int r = 0; r < 6; ++r) {
            const int idx = r * 256 + tid;
            const int row = idx / 24, cc = idx % 24;
            *(uint4*)&sB[row * LDK + cc * 8] =
                *(const uint4*)&wbx[(size_t)row * DIN + kh + cc * 8];
        }
        __syncthreads();
        // conv+SiLU: thread -> row tid>>2, 48 cols starting (tid&3)*48
        {
            const int row = tid >> 2;
            const int cb0 = (tid & 3) * 48;
#pragma unroll
            for (int grp = 0; grp < 6; ++grp) {
                const int c = cb0 + grp * 8;
                const short8 t0 = *(const short8*)&sXZ[(row + 0) * LDK + c];
                const short8 t1 = *(const short8*)&sXZ[(row + 1) * LDK + c];
                const short8 t2 = *(const short8*)&sXZ[(row + 2) * LDK + c];
                const short8 t3 = *(const short8*)&sXZ[(row + 3) * LDK + c];
                unsigned int pk[4];
#pragma unroll
                for (int j = 0; j < 8; ++j) {
                    const float4 w4 = scw[c + j];
                    float s = scb[c + j];
                    s += bf2f((unsigned short)t0[j]) * w4.x;
                    s += bf2f((unsigned short)t1[j]) * w4.y;
                    s += bf2f((unsigned short)t2[j]) * w4.z;
                    s += bf2f((unsigned short)t3[j]) * w4.w;
                    const unsigned short us = f2bf(silu_f(s));
                    if (j & 1) pk[j >> 1] |= ((unsigned int)us) << 16;
                    else       pk[j >> 1]  = us;
                }
                *(uint4*)&sA[row * LDK + c] = *(uint4*)pk;
            }
        }
        __syncthreads();
        // write xcb (coalesced rounds from sA)
#pragma unroll
        for (int r = 0; r < 6; ++r) {
            const int idx = r * 256 + tid;
            const int row = idx / 24, cc = idx % 24;
            *(uint4*)&xcb[(size_t)(m0 + row) * DIN + kh + cc * 8] =
                *(const uint4*)&sA[row * LDK + cc * 8];
        }
        // MFMA
#pragma unroll
        for (int ks = 0; ks < 6; ++ks) {
            short8 af[2], bf[2];
#pragma unroll
            for (int im = 0; im < 2; ++im)
                af[im] = *(const short8*)&sA[(wm*32 + im*16 + mlan) * LDK + ks*32 + kq8];
#pragma unroll
            for (int jn = 0; jn < 2; ++jn)
                bf[jn] = *(const short8*)&sB[(wn*32 + jn*16 + mlan) * LDK + ks*32 + kq8];
#pragma unroll
            for (int im = 0; im < 2; ++im)
#pragma unroll
                for (int jn = 0; jn < 2; ++jn)
                    acc[im][jn] = __builtin_amdgcn_mfma_f32_16x16x32_bf16(
                        af[im], bf[jn], acc[im][jn], 0, 0, 0);
        }
    }
    const int quad = lane >> 4;
#pragma unroll
    for (int im = 0; im < 2; ++im)
#pragma unroll
        for (int jn = 0; jn < 2; ++jn) {
            const int n = wn*32 + jn*16 + mlan;
            if (n < 48) {
                const int ml = wm*32 + im*16 + quad*4;
#pragma unroll
                for (int r = 0; r < 4; ++r) {
                    const float v = acc[im][jn][r];
                    xdbl[(size_t)(m0 + ml + r) * 48 + n] = v;
                    if (n < DTRANK) sdt[ml + r][n] = v;   // stash dt cols for fused dt_proj
                }
            }
        }
    // ---- fused dt_proj: dlt = softplus(sdt @ Wdt^T + 2*b_dt), 64 rows x 384 d ----
    __syncthreads();
    {
        // phase 1: d = tid (0..255), all 64 rows (sdt reads are wave-broadcast)
        float w1[DTRANK];
#pragma unroll
        for (int r = 0; r < DTRANK; ++r) w1[r] = Wdt[tid * DTRANK + r];
        const float b1 = 2.f * bdt[tid];
#pragma unroll
        for (int row = 0; row < 64; ++row) {
            float s = b1;
#pragma unroll
            for (int r = 0; r < DTRANK; ++r) s += sdt[row][r] * w1[r];
            dlt[(size_t)(m0 + row) * DIN + tid] = __float2bfloat16(softplus_f(s));
        }
        // phase 2: d = 256 + (tid & 127), rows (tid>>7)*32 .. +32
        const int d2 = 256 + (tid & 127);
        float w2[DTRANK];
#pragma unroll
        for (int r = 0; r < DTRANK; ++r) w2[r] = Wdt[d2 * DTRANK + r];
        const float b2 = 2.f * bdt[d2];
        const int r0 = (tid >> 7) * 32;
#pragma unroll
        for (int rr = 0; rr < 32; ++rr) {
            const int row = r0 + rr;
            float s = b2;
#pragma unroll
            for (int r = 0; r < DTRANK; ++r) s += sdt[row][r] * w2[r];
            dlt[(size_t)(m0 + row) * DIN + d2] = __float2bfloat16(softplus_f(s));
        }
    }
}

// ---------------- scan phase a: upfront loads; stores S + dsum --------------------
__launch_bounds__(128)
__global__ void k_scan_a(const __hip_bfloat16* __restrict__ dlt,
                         const __hip_bfloat16* __restrict__ xcb,
                         const float* __restrict__ xdbl, const float* __restrict__ A_log,
                         float* __restrict__ S, float* __restrict__ Dsum) {
    __shared__ float sBC[T_CHUNK * 32];
    const int tid = threadIdx.x;
    const int g = blockIdx.x, b = blockIdx.z;
    const size_t row0 = (size_t)b * L_SEQ + g * T_CHUNK;
    if (tid < T_CHUNK * 8) {
        const int r = tid >> 3, q = (tid & 7) * 4;
        *(float4*)&sBC[r * 32 + q] = *(const float4*)&xdbl[(row0 + r) * 48 + 12 + q];
    }
    const int d = blockIdx.y * 128 + tid;
    unsigned short dv_a[T_CHUNK], uv_a[T_CHUNK];
#pragma unroll
    for (int t = 0; t < T_CHUNK; ++t)
        dv_a[t] = *(const unsigned short*)&dlt[(row0 + t) * DIN + d];
#pragma unroll
    for (int t = 0; t < T_CHUNK; ++t)
        uv_a[t] = *(const unsigned short*)&xcb[(row0 + t) * DIN + d];
    float A[DSTATE];
#pragma unroll
    for (int n = 0; n < DSTATE; n += 4) {
        const float4 a4 = *(const float4*)&A_log[d * DSTATE + n];
        A[n] = -__expf(a4.x); A[n+1] = -__expf(a4.y);
        A[n+2] = -__expf(a4.z); A[n+3] = -__expf(a4.w);
    }
    __syncthreads();
    float h[DSTATE] = {};
    float dsum = 0.f;
#pragma unroll
    for (int t = 0; t < T_CHUNK; ++t) {
        const float dv = bf2f(dv_a[t]);
        const float uv = bf2f(uv_a[t]);
        const float dub = dv * uv;
        dsum += dv;
#pragma unroll
        for (int n = 0; n < DSTATE; ++n) {
            const float e = __expf(dv * A[n]);
            h[n] = e * h[n] + dub * sBC[t*32 + n];
        }
    }
    float* Sp = S + (size_t)g * NCH + (size_t)(b * DIN + d) * DSTATE;
#pragma unroll
    for (int n = 0; n < DSTATE; n += 4)
        *(float4*)&Sp[n] = make_float4(h[n], h[n+1], h[n+2], h[n+3]);
    Dsum[(size_t)g * NBD + b * DIN + d] = dsum;
}

// -------- scan phase b: combine; P recomputed from dsum; S becomes entering state ---
__launch_bounds__(256)
__global__ void k_scan_b(float* __restrict__ Sh, const float* __restrict__ Dsum,
                         const float* __restrict__ A_log) {
    const int ch = blockIdx.x * 256 + threadIdx.x;
    const float a = -__expf(A_log[ch % (DIN * DSTATE)]);
    const int bd = ch >> 4;
    float h = 0.f;
    for (int g = 0; g < G_CHUNKS; ++g) {
        const size_t i = (size_t)g * NCH + ch;
        const float s = Sh[i];
        const float p = __expf(a * Dsum[(size_t)g * NBD + bd]);
        Sh[i] = h;
        h = p * h + s;
    }
}

// ---------------- scan phase c: replay + y + D*u + gate -> yb bf16 ----------------
__launch_bounds__(128)
__global__ void k_scan_c(const __hip_bfloat16* __restrict__ dlt,
                         const __hip_bfloat16* __restrict__ xcb,
                         const float* __restrict__ xdbl, const float* __restrict__ A_log,
                         const float* __restrict__ Hst, const __hip_bfloat16* __restrict__ xzb,
                         const float* __restrict__ Dv, __hip_bfloat16* __restrict__ yb) {
    __shared__ float sBC[T_CHUNK * 32];
    const int tid = threadIdx.x;
    const int g = blockIdx.x, b = blockIdx.z;
    const size_t row0 = (size_t)b * L_SEQ + g * T_CHUNK;
    if (tid < T_CHUNK * 8) {
        const int r = tid >> 3, q = (tid & 7) * 4;
        *(float4*)&sBC[r * 32 + q] = *(const float4*)&xdbl[(row0 + r) * 48 + 12 + q];
    }
    const int d = blockIdx.y * 128 + tid;
    unsigned short dv_a[T_CHUNK], uv_a[T_CHUNK], zz_a[T_CHUNK];
#pragma unroll
    for (int t = 0; t < T_CHUNK; ++t)
        dv_a[t] = *(const unsigned short*)&dlt[(row0 + t) * DIN + d];
#pragma unroll
    for (int t = 0; t < T_CHUNK; ++t)
        uv_a[t] = *(const unsigned short*)&xcb[(row0 + t) * DIN + d];
#pragma unroll
    for (int t = 0; t < T_CHUNK; ++t)
        zz_a[t] = *(const unsigned short*)&xzb[(row0 + t) * DIN2 + DIN + d];
    float A[DSTATE];
#pragma unroll
    for (int n = 0; n < DSTATE; n += 4) {
        const float4 a4 = *(const float4*)&A_log[d * DSTATE + n];
        A[n] = -__expf(a4.x); A[n+1] = -__expf(a4.y);
        A[n+2] = -__expf(a4.z); A[n+3] = -__expf(a4.w);
    }
    float h[DSTATE];
    const float* Hp = Hst + (size_t)g * NCH + (size_t)(b * DIN + d) * DSTATE;
#pragma unroll
    for (int n = 0; n < DSTATE; n += 4) {
        const float4 h4 = *(const float4*)&Hp[n];
        h[n] = h4.x; h[n+1] = h4.y; h[n+2] = h4.z; h[n+3] = h4.w;
    }
    const float Dd = Dv[d];
    __hip_bfloat16* yl = yb + row0 * DIN + d;
    __syncthreads();
#pragma unroll
    for (int t = 0; t < T_CHUNK; ++t) {
        const float dv = bf2f(dv_a[t]);
        const float uv = bf2f(uv_a[t]);
        const float dub = dv * uv;
        float y0 = 0.f, y1 = 0.f, y2 = 0.f, y3 = 0.f;
#pragma unroll
        for (int n = 0; n < DSTATE; n += 4) {
            float e;
            e = __expf(dv * A[n  ]); h[n  ] = e * h[n  ] + dub * sBC[t*32 + n  ]; y0 += h[n  ] * sBC[t*32 + 16 + n  ];
            e = __expf(dv * A[n+1]); h[n+1] = e * h[n+1] + dub * sBC[t*32 + n+1]; y1 += h[n+1] * sBC[t*32 + 16 + n+1];
            e = __expf(dv * A[n+2]); h[n+2] = e * h[n+2] + dub * sBC[t*32 + n+2]; y2 += h[n+2] * sBC[t*32 + 16 + n+2];
            e = __expf(dv * A[n+3]); h[n+3] = e * h[n+3] + dub * sBC[t*32 + n+3]; y3 += h[n+3] * sBC[t*32 + 16 + n+3];
        }
        const float y = (y0 + y1) + (y2 + y3);
        yl[(size_t)t * DIN] = __float2bfloat16((y + Dd * uv) * silu_f(bf2f(zz_a[t])));
    }
}

// ---------------- out_proj: out(b,192,l) f32 = yb(m,384) @ wbo(192,384)^T ----------
// grid (2 n-tiles, 256 m-tiles). Epilogue: LDS transpose -> coalesced stores along l
// (fixes ~5x partial-line write amplification of the old lane-scatter epilogue).
__launch_bounds__(256)
__global__ void k_gemm_out(const __hip_bfloat16* __restrict__ A,
                           const __hip_bfloat16* __restrict__ B,
                           float* __restrict__ out) {
    __shared__ __align__(16) char smem[(64 + 96) * LDK * 2];   // 62.5 KB
    __hip_bfloat16* sA = (__hip_bfloat16*)smem;
    __hip_bfloat16* sB = sA + 64 * LDK;
    float* sOut = (float*)smem;            // aliased after final barrier (26.1 KB)
    const int tid = threadIdx.x;
    const int lane = tid & 63;
    const int wave = tid >> 6;
    const int wm = wave >> 1, wn = wave & 1;
    const int m0 = blockIdx.y * 64;
    const int n0 = blockIdx.x * 96;
    const int mlan = lane & 15;
    const int kq8 = (lane >> 4) * 8;

    floatx4 acc[2][3];
#pragma unroll
    for (int i = 0; i < 2; ++i)
#pragma unroll
        for (int j = 0; j < 3; ++j) acc[i][j] = (floatx4){0.f, 0.f, 0.f, 0.f};

    for (int kh = 0; kh < DIN; kh += 192) {
        uint4 va[6], vb[9];
#pragma unroll
        for (int r = 0; r < 6; ++r) {
            const int idx = r * 256 + tid, row = idx / 24, cc = idx % 24;
            va[r] = *(const uint4*)&A[(size_t)(m0 + row) * DIN + kh + cc * 8];
        }
#pragma unroll
        for (int r = 0; r < 9; ++r) {
            const int idx = r * 256 + tid, row = idx / 24, cc = idx % 24;
            vb[r] = *(const uint4*)&B[(size_t)(n0 + row) * DIN + kh + cc * 8];
        }
        if (kh) __syncthreads();
#pragma unroll
        for (int r = 0; r < 6; ++r) {
            const int idx = r * 256 + tid, row = idx / 24, cc = idx % 24;
            *(uint4*)&sA[row * LDK + cc * 8] = va[r];
        }
#pragma unroll
        for (int r = 0; r < 9; ++r) {
            const int idx = r * 256 + tid, row = idx / 24, cc = idx % 24;
            *(uint4*)&sB[row * LDK + cc * 8] = vb[r];
        }
        __syncthreads();
#pragma unroll
        for (int ks = 0; ks < 6; ++ks) {
            short8 af[2], bf[3];
#pragma unroll
            for (int im = 0; im < 2; ++im)
                af[im] = *(const short8*)&sA[(wm*32 + im*16 + mlan) * LDK + ks*32 + kq8];
#pragma unroll
            for (int jn = 0; jn < 3; ++jn)
                bf[jn] = *(const short8*)&sB[(wn*48 + jn*16 + mlan) * LDK + ks*32 + kq8];
#pragma unroll
            for (int im = 0; im < 2; ++im)
#pragma unroll
                for (int jn = 0; jn < 3; ++jn)
                    acc[im][jn] = __builtin_amdgcn_mfma_f32_16x16x32_bf16(
                        af[im], bf[jn], acc[im][jn], 0, 0, 0);
        }
    }
    // epilogue: stash n-major (padded 68) in LDS, store out coalesced along l
    const int quad = lane >> 4;
    __syncthreads();                          // all MFMA reads of sA/sB done
#pragma unroll
    for (int im = 0; im < 2; ++im)
#pragma unroll
        for (int jn = 0; jn < 3; ++jn) {
            const int nl = wn*48 + jn*16 + mlan;
            const int ml = wm*32 + im*16 + quad*4;
            *(float4*)&sOut[nl * 68 + ml] =
                make_float4(acc[im][jn][0], acc[im][jn][1], acc[im][jn][2], acc[im][jn][3]);
        }
    __syncthreads();
    const int bb = m0 >> 12, l0 = m0 & (L_SEQ - 1);
#pragma unroll
    for (int it = 0; it < 24; ++it) {
        const int idx = it * 256 + tid;
        const int n = idx >> 6, ml = idx & 63;
        out[((size_t)bb * DIMC + n0 + n) * L_SEQ + l0 + ml] = sOut[n * 68 + ml];
    }
}

// ---------------- launcher ----------------
extern "C" void kernel_launch(void* const* d_in, const int* in_sizes, int n_in,
                              void* d_out, int out_size, void* d_ws, size_t ws_size,
                              hipStream_t stream) {
    const float* x      = (const float*)d_in[0];
    const float* W_in   = (const float*)d_in[1];
    const float* conv_w = (const float*)d_in[2];
    const float* conv_b = (const float*)d_in[3];
    const float* W_x    = (const float*)d_in[4];
    const float* W_dt   = (const float*)d_in[5];
    const float* b_dt   = (const float*)d_in[6];
    const float* A_log  = (const float*)d_in[7];
    const float* Dvec   = (const float*)d_in[8];
    const float* W_out  = (const float*)d_in[9];
    float* out = (float*)d_out;

    char* p = (char*)d_ws;
    __hip_bfloat16* wbi  = (__hip_bfloat16*)p; p += (size_t)NWI * 2;
    __hip_bfloat16* wbo  = (__hip_bfloat16*)p; p += (size_t)NWO * 2;
    __hip_bfloat16* wbx  = (__hip_bfloat16*)p; p += (size_t)NWX * 2;
    __hip_bfloat16* xzb  = (__hip_bfloat16*)p; p += (size_t)NM * DIN2 * 2;   // 25MB
    __hip_bfloat16* xcb  = (__hip_bfloat16*)p; p += (size_t)NM * DIN * 2;    // 12.6MB
    float*          xdbl = (float*)p;          p += (size_t)NM * 48 * 4;     // 3.1MB
    __hip_bfloat16* dlt  = (__hip_bfloat16*)p; p += (size_t)NM * DIN * 2;    // 12.6MB
    __hip_bfloat16* yb   = (__hip_bfloat16*)p; p += (size_t)NM * DIN * 2;    // 12.6MB
    float*          S    = (float*)p;          p += (size_t)G_CHUNKS * NCH * 4;  // 25MB
    float*          Dsum = (float*)p;          p += (size_t)G_CHUNKS * NBD * 4;  // 1.6MB

    // 1. weight conversion (W_x padded to 64 rows)
    k_cvt_w<<<dim3((NWI + NWO + NWX + 255) / 256), 256, 0, stream>>>(
        W_in, W_out, W_x, wbi, wbo, wbx);
    // 2. in_proj (fused transpose+convert of x): xzb(m,768) bf16
    k_gemm_in<<<dim3(DIN2/128, NM/64), 256, 0, stream>>>(x, wbi, xzb);
    // 3. x_proj with fused conv + fused dt_proj: xcb, xdbl, dlt
    k_gemm_xp<<<dim3(NM/64), 256, 0, stream>>>(xzb, wbx, conv_w, conv_b,
                                               W_dt, b_dt, xcb, xdbl, dlt);
    // 4. chunked selective scan (G=256, T=16)
    k_scan_a<<<dim3(G_CHUNKS, 3, NB), 128, 0, stream>>>(dlt, xcb, xdbl, A_log, S, Dsum);
    k_scan_b<<<dim3(NCH/256), 256, 0, stream>>>(S, Dsum, A_log);
    k_scan_c<<<dim3(G_CHUNKS, 3, NB), 128, 0, stream>>>(dlt, xcb, xdbl, A_log,
                                                        S, xzb, Dvec, yb);
    // 5. out_proj: out(b,192,l) = yb(m,384) @ wbo(192,384)^T (coalesced epilogue)
    k_gemm_out<<<dim3(DIMC/96, NM/64), 256, 0, stream>>>(yb, wbo, out);
}

// Round 13
// 224.500 us; speedup vs baseline: 1.1030x; 1.1030x over previous
//
#include <hip/hip_runtime.h>
#include <hip/hip_bf16.h>
#include <math.h>

// ---------------- problem constants ----------------
#define L_SEQ 4096            // H*W
#define NB    4
#define DIMC  192
#define DIN   384             // d_inner
#define DIN2  768
#define DTRANK 12
#define DSTATE 16
#define NKX   44              // dt_rank + 2*d_state
#define G_CHUNKS 128
#define T_CHUNK  32           // L_SEQ / G_CHUNKS
#define NCH  (NB*DIN*DSTATE)  // 24576 scan channels
#define NBD  (NB*DIN)         // 1536 (b,d) channels
#define NM   (NB*L_SEQ)       // 16384 (b,l) rows
#define NBIG 448              // padded rows of fused x_proj weight (32 BC + 384 dt + pad)
#define LDK  200              // padded LDS row

typedef __attribute__((ext_vector_type(8))) short short8;     // 8 bf16 = 4 VGPRs
typedef __attribute__((ext_vector_type(4))) float floatx4;

__device__ __forceinline__ float silu_f(float v) {
    return v / (1.f + __expf(-v));
}
// softplus via hardware v_log_f32 (log1pf is a slow libm path)
__device__ __forceinline__ float softplus_f(float v) {
    return fmaxf(v, 0.f) + __logf(1.f + __expf(-fabsf(v)));
}
__device__ __forceinline__ float bf2f(unsigned short u) {
    union { unsigned int i; float f; } c; c.i = ((unsigned int)u) << 16; return c.f;
}

// ---------------- convert + transpose x: (b,c,l) f32 -> (b*l, c) bf16 ----------------
__launch_bounds__(256)
__global__ void k_cvt_x(const float* __restrict__ x, __hip_bfloat16* __restrict__ xb) {
    __shared__ float s[32][33];
    const int b = blockIdx.z, c0 = blockIdx.y * 32, l0 = blockIdx.x * 32;
    const int tx = threadIdx.x, ty = threadIdx.y;   // (32, 8)
    const float* xp = x + ((size_t)b * DIMC + c0) * L_SEQ + l0;
#pragma unroll
    for (int r = 0; r < 4; ++r)
        s[ty + r*8][tx] = xp[(size_t)(ty + r*8) * L_SEQ + tx];
    __syncthreads();
    __hip_bfloat16* op = xb + ((size_t)b * L_SEQ + l0) * DIMC + c0;
#pragma unroll
    for (int r = 0; r < 4; ++r) {
        const int lr = ty + r*8;
        op[(size_t)lr * DIMC + tx] = __float2bfloat16(s[tx][lr]);
    }
}

// ------- weights: W_in, W_out -> bf16; build Wbig(448x384) = [Wx[12:44]; Wdt@Wx[:12]; 0] ----
#define NWI (DIN2*DIMC)        // 147456
#define NWO (DIMC*DIN)         // 73728
#define NWBIG (NBIG*DIN)       // 172032
__launch_bounds__(256)
__global__ void k_cvt_w(const float* __restrict__ W_in, const float* __restrict__ W_out,
                        const float* __restrict__ W_x, const float* __restrict__ W_dt,
                        __hip_bfloat16* __restrict__ wbi, __hip_bfloat16* __restrict__ wbo,
                        __hip_bfloat16* __restrict__ wbig) {
    const int i = blockIdx.x * 256 + threadIdx.x;
    if (i < NWI) {
        wbi[i] = __float2bfloat16(W_in[i]);
    } else if (i < NWI + NWO) {
        const int j = i - NWI;
        wbo[j] = __float2bfloat16(W_out[j]);
    } else if (i < NWI + NWO + NWBIG) {
        const int j = i - NWI - NWO;
        const int r = j / DIN, c = j - r * DIN;
        float v;
        if (r < 32) {
            v = W_x[(size_t)(DTRANK + r) * DIN + c];        // B,C rows
        } else if (r < 32 + DIN) {
            const int d = r - 32;                           // composite dt row
            v = 0.f;
#pragma unroll
            for (int q = 0; q < DTRANK; ++q)
                v += W_dt[d * DTRANK + q] * W_x[(size_t)q * DIN + c];
        } else {
            v = 0.f;                                        // pad rows 416..447
        }
        wbig[j] = __float2bfloat16(v);
    }
}

// ---------------- bf16 NT MFMA GEMM, full-K staging (small-K regime) ----------------
// C[m][n] = sum_k A[m][k]*B[n][k]. BM=64. K staged in 192-wide chunks via VGPRs into
// padded LDS (row stride 200). ONE barrier per chunk. 4 waves 2x2, wave tile 32xBN/2.
// OUTMODE 0: bf16 row-major ldc            (in_proj -> xzb)
// OUTMODE 1: f32 at out[b][n][l], m=b*L+l  (out_proj) — LDS-transpose coalesced epilogue
// OUTMODE 3: x_proj fused m-major: n<32 -> xbc f32(m,32);
//            32<=n<416: dlt[m][n-32] bf16 = softplus(v + 2*b_dt[n-32]); n>=416 dropped
template<int BN, int OUTMODE>
__launch_bounds__(256)
__global__ void k_gemm(const __hip_bfloat16* __restrict__ A,
                       const __hip_bfloat16* __restrict__ B,
                       float* __restrict__ Cf, __hip_bfloat16* __restrict__ Cb,
                       __hip_bfloat16* __restrict__ Cb2, const float* __restrict__ bdt,
                       int K, int ldc) {
    constexpr int WN = BN / 2;
    constexpr int TN = WN / 16;
    constexpr int NCA = 6;                   // A chunks/thread: 64*24/256
    constexpr int NCB = BN * 24 / 256;       // B chunks/thread
    __shared__ __align__(16) char smem[(64 + BN) * LDK * 2];
    __hip_bfloat16* sA = (__hip_bfloat16*)smem;
    __hip_bfloat16* sB = sA + 64 * LDK;
    float* sOut = (float*)smem;              // aliased for OUTMODE 1 epilogue

    const int tid = threadIdx.x;
    const int lane = tid & 63;
    const int wave = tid >> 6;
    const int wm = wave >> 1, wn = wave & 1;
    const int m0 = blockIdx.x * 64;
    const int n0 = blockIdx.y * BN;
    const int mlan = lane & 15;
    const int kq8 = (lane >> 4) * 8;

    floatx4 acc[2][TN];
#pragma unroll
    for (int i = 0; i < 2; ++i)
#pragma unroll
        for (int j = 0; j < TN; ++j) acc[i][j] = (floatx4){0.f, 0.f, 0.f, 0.f};

    for (int kh = 0; kh < K; kh += 192) {
        if (kh) __syncthreads();
        uint4 va[NCA], vb[NCB];
#pragma unroll
        for (int r = 0; r < NCA; ++r) {
            const int c = r * 256 + tid, row = c / 24, cc = c - row * 24;
            va[r] = *(const uint4*)&A[(size_t)(m0 + row) * K + kh + cc * 8];
        }
#pragma unroll
        for (int r = 0; r < NCB; ++r) {
            const int c = r * 256 + tid, row = c / 24, cc = c - row * 24;
            vb[r] = *(const uint4*)&B[(size_t)(n0 + row) * K + kh + cc * 8];
        }
#pragma unroll
        for (int r = 0; r < NCA; ++r) {
            const int c = r * 256 + tid, row = c / 24, cc = c - row * 24;
            *(uint4*)&sA[row * LDK + cc * 8] = va[r];
        }
#pragma unroll
        for (int r = 0; r < NCB; ++r) {
            const int c = r * 256 + tid, row = c / 24, cc = c - row * 24;
            *(uint4*)&sB[row * LDK + cc * 8] = vb[r];
        }
        __syncthreads();
#pragma unroll
        for (int ks = 0; ks < 6; ++ks) {
            short8 af[2], bf[TN];
#pragma unroll
            for (int im = 0; im < 2; ++im)
                af[im] = *(const short8*)&sA[(wm*32 + im*16 + mlan) * LDK + ks*32 + kq8];
#pragma unroll
            for (int jn = 0; jn < TN; ++jn)
                bf[jn] = *(const short8*)&sB[(wn*WN + jn*16 + mlan) * LDK + ks*32 + kq8];
#pragma unroll
            for (int im = 0; im < 2; ++im)
#pragma unroll
                for (int jn = 0; jn < TN; ++jn)
                    acc[im][jn] = __builtin_amdgcn_mfma_f32_16x16x32_bf16(
                        af[im], bf[jn], acc[im][jn], 0, 0, 0);
        }
    }

    const int quad = lane >> 4;
    if (OUTMODE == 1) {
        // coalesced epilogue: stash n-major (pad 68) in LDS, store along l
        __syncthreads();
#pragma unroll
        for (int im = 0; im < 2; ++im)
#pragma unroll
            for (int jn = 0; jn < TN; ++jn) {
                const int nl = wn*WN + jn*16 + mlan;
                const int ml = wm*32 + im*16 + quad*4;
                *(float4*)&sOut[nl * 68 + ml] =
                    make_float4(acc[im][jn][0], acc[im][jn][1],
                                acc[im][jn][2], acc[im][jn][3]);
            }
        __syncthreads();
        const int bb = m0 >> 12, l0m = m0 & (L_SEQ - 1);
        constexpr int NIT = BN * 64 / 256;
#pragma unroll
        for (int it = 0; it < NIT; ++it) {
            const int idx = it * 256 + tid;
            const int n = idx >> 6, ml = idx & 63;
            Cf[((size_t)bb * DIMC + n0 + n) * L_SEQ + l0m + ml] = sOut[n * 68 + ml];
        }
        return;
    }
#pragma unroll
    for (int im = 0; im < 2; ++im) {
#pragma unroll
        for (int jn = 0; jn < TN; ++jn) {
            const int n = n0 + wn*WN + jn*16 + mlan;
            const int mb = m0 + wm*32 + im*16 + quad*4;
#pragma unroll
            for (int r = 0; r < 4; ++r) {
                const int m = mb + r;
                const float v = acc[im][jn][r];
                if (OUTMODE == 0) {
                    Cb[(size_t)m * ldc + n] = __float2bfloat16(v);
                } else {
                    if (n < 32) {
                        Cf[(size_t)m * 32 + n] = v;
                    } else if (n < 32 + DIN) {
                        Cb2[(size_t)m * DIN + (n - 32)] =
                            __float2bfloat16(softplus_f(v + 2.f * bdt[n - 32]));
                    }
                }
            }
        }
    }
}

// ---------------- depthwise causal conv4 + SiLU: xzb bf16 (stride 768) -> bf16 -----
__launch_bounds__(256)
__global__ void k_conv(const __hip_bfloat16* __restrict__ xz, const float* __restrict__ cw,
                       const float* __restrict__ cb, __hip_bfloat16* __restrict__ xcb) {
    const int idx = blockIdx.x * 256 + threadIdx.x;   // m*DIN + d
    const int d = idx % DIN;
    const int m = idx / DIN;
    const int l = m & (L_SEQ - 1);
    const float4 w4 = *(const float4*)&cw[d * 4];
    float s = cb[d];
    const float w[4] = {w4.x, w4.y, w4.z, w4.w};
#pragma unroll
    for (int k = 0; k < 4; ++k) {
        const int ll = l - 3 + k;
        if (ll >= 0) s += __bfloat162float(xz[(size_t)(m - 3 + k) * DIN2 + d]) * w[k];
    }
    xcb[idx] = __float2bfloat16(silu_f(s));
}

// ---------------- scan phase a: m-major upfront loads; stores S + dsum ------------
__launch_bounds__(128)
__global__ void k_scan_a(const __hip_bfloat16* __restrict__ dlt,
                         const __hip_bfloat16* __restrict__ xcb,
                         const float* __restrict__ xbc, const float* __restrict__ A_log,
                         float* __restrict__ S, float* __restrict__ Dsum) {
    __shared__ float sBC[T_CHUNK * 32];
    const int tid = threadIdx.x;
    const int g = blockIdx.x, b = blockIdx.z;
    const size_t row0 = (size_t)b * L_SEQ + g * T_CHUNK;
    for (int i = tid; i < T_CHUNK * 8; i += 128)
        *(float4*)&sBC[i * 4] = *(const float4*)&xbc[row0 * 32 + i * 4];
    const int d = blockIdx.y * 128 + tid;
    unsigned short dv_a[T_CHUNK], uv_a[T_CHUNK];
#pragma unroll
    for (int t = 0; t < T_CHUNK; ++t)
        dv_a[t] = *(const unsigned short*)&dlt[(row0 + t) * DIN + d];
#pragma unroll
    for (int t = 0; t < T_CHUNK; ++t)
        uv_a[t] = *(const unsigned short*)&xcb[(row0 + t) * DIN + d];
    float A[DSTATE];
#pragma unroll
    for (int n = 0; n < DSTATE; n += 4) {
        const float4 a4 = *(const float4*)&A_log[d * DSTATE + n];
        A[n] = -__expf(a4.x); A[n+1] = -__expf(a4.y);
        A[n+2] = -__expf(a4.z); A[n+3] = -__expf(a4.w);
    }
    __syncthreads();
    float h[DSTATE] = {};
    float dsum = 0.f;
#pragma unroll
    for (int t = 0; t < T_CHUNK; ++t) {
        const float dv = bf2f(dv_a[t]);
        const float uv = bf2f(uv_a[t]);
        const float dub = dv * uv;
        dsum += dv;
#pragma unroll
        for (int n = 0; n < DSTATE; ++n) {
            const float e = __expf(dv * A[n]);
            h[n] = e * h[n] + dub * sBC[t*32 + n];
        }
    }
    float* Sp = S + (size_t)g * NCH + (size_t)(b * DIN + d) * DSTATE;
#pragma unroll
    for (int n = 0; n < DSTATE; n += 4)
        *(float4*)&Sp[n] = make_float4(h[n], h[n+1], h[n+2], h[n+3]);
    Dsum[(size_t)g * NBD + b * DIN + d] = dsum;
}

// -------- scan phase b: combine; P recomputed from dsum; S becomes entering state ---
__launch_bounds__(256)
__global__ void k_scan_b(float* __restrict__ Sh, const float* __restrict__ Dsum,
                         const float* __restrict__ A_log) {
    const int ch = blockIdx.x * 256 + threadIdx.x;
    const float a = -__expf(A_log[ch % (DIN * DSTATE)]);
    const int bd = ch >> 4;
    float h = 0.f;
    for (int g = 0; g < G_CHUNKS; ++g) {
        const size_t i = (size_t)g * NCH + ch;
        const float s = Sh[i];
        const float p = __expf(a * Dsum[(size_t)g * NBD + bd]);
        Sh[i] = h;
        h = p * h + s;
    }
}

// ---------------- scan phase c: replay + y + D*u + gate -> yb bf16 ----------------
__launch_bounds__(128)
__global__ void k_scan_c(const __hip_bfloat16* __restrict__ dlt,
                         const __hip_bfloat16* __restrict__ xcb,
                         const float* __restrict__ xbc, const float* __restrict__ A_log,
                         const float* __restrict__ Hst, const __hip_bfloat16* __restrict__ xzb,
                         const float* __restrict__ Dv, __hip_bfloat16* __restrict__ yb) {
    __shared__ float sBC[T_CHUNK * 32];
    const int tid = threadIdx.x;
    const int g = blockIdx.x, b = blockIdx.z;
    const size_t row0 = (size_t)b * L_SEQ + g * T_CHUNK;
    for (int i = tid; i < T_CHUNK * 8; i += 128)
        *(float4*)&sBC[i * 4] = *(const float4*)&xbc[row0 * 32 + i * 4];
    const int d = blockIdx.y * 128 + tid;
    unsigned short dv_a[T_CHUNK], uv_a[T_CHUNK], zz_a[T_CHUNK];
#pragma unroll
    for (int t = 0; t < T_CHUNK; ++t)
        dv_a[t] = *(const unsigned short*)&dlt[(row0 + t) * DIN + d];
#pragma unroll
    for (int t = 0; t < T_CHUNK; ++t)
        uv_a[t] = *(const unsigned short*)&xcb[(row0 + t) * DIN + d];
#pragma unroll
    for (int t = 0; t < T_CHUNK; ++t)
        zz_a[t] = *(const unsigned short*)&xzb[(row0 + t) * DIN2 + DIN + d];
    float A[DSTATE];
#pragma unroll
    for (int n = 0; n < DSTATE; n += 4) {
        const float4 a4 = *(const float4*)&A_log[d * DSTATE + n];
        A[n] = -__expf(a4.x); A[n+1] = -__expf(a4.y);
        A[n+2] = -__expf(a4.z); A[n+3] = -__expf(a4.w);
    }
    float h[DSTATE];
    const float* Hp = Hst + (size_t)g * NCH + (size_t)(b * DIN + d) * DSTATE;
#pragma unroll
    for (int n = 0; n < DSTATE; n += 4) {
        const float4 h4 = *(const float4*)&Hp[n];
        h[n] = h4.x; h[n+1] = h4.y; h[n+2] = h4.z; h[n+3] = h4.w;
    }
    const float Dd = Dv[d];
    __hip_bfloat16* yl = yb + row0 * DIN + d;
    __syncthreads();
#pragma unroll
    for (int t = 0; t < T_CHUNK; ++t) {
        const float dv = bf2f(dv_a[t]);
        const float uv = bf2f(uv_a[t]);
        const float dub = dv * uv;
        float y0 = 0.f, y1 = 0.f, y2 = 0.f, y3 = 0.f;
#pragma unroll
        for (int n = 0; n < DSTATE; n += 4) {
            float e;
            e = __expf(dv * A[n  ]); h[n  ] = e * h[n  ] + dub * sBC[t*32 + n  ]; y0 += h[n  ] * sBC[t*32 + 16 + n  ];
            e = __expf(dv * A[n+1]); h[n+1] = e * h[n+1] + dub * sBC[t*32 + n+1]; y1 += h[n+1] * sBC[t*32 + 16 + n+1];
            e = __expf(dv * A[n+2]); h[n+2] = e * h[n+2] + dub * sBC[t*32 + n+2]; y2 += h[n+2] * sBC[t*32 + 16 + n+2];
            e = __expf(dv * A[n+3]); h[n+3] = e * h[n+3] + dub * sBC[t*32 + n+3]; y3 += h[n+3] * sBC[t*32 + 16 + n+3];
        }
        const float y = (y0 + y1) + (y2 + y3);
        yl[(size_t)t * DIN] = __float2bfloat16((y + Dd * uv) * silu_f(bf2f(zz_a[t])));
    }
}

// ---------------- launcher ----------------
extern "C" void kernel_launch(void* const* d_in, const int* in_sizes, int n_in,
                              void* d_out, int out_size, void* d_ws, size_t ws_size,
                              hipStream_t stream) {
    const float* x      = (const float*)d_in[0];
    const float* W_in   = (const float*)d_in[1];
    const float* conv_w = (const float*)d_in[2];
    const float* conv_b = (const float*)d_in[3];
    const float* W_x    = (const float*)d_in[4];
    const float* W_dt   = (const float*)d_in[5];
    const float* b_dt   = (const float*)d_in[6];
    const float* A_log  = (const float*)d_in[7];
    const float* Dvec   = (const float*)d_in[8];
    const float* W_out  = (const float*)d_in[9];
    float* out = (float*)d_out;

    char* p = (char*)d_ws;
    __hip_bfloat16* xb   = (__hip_bfloat16*)p; p += (size_t)NM * DIMC * 2;
    __hip_bfloat16* wbi  = (__hip_bfloat16*)p; p += (size_t)NWI * 2;
    __hip_bfloat16* wbo  = (__hip_bfloat16*)p; p += (size_t)NWO * 2;
    __hip_bfloat16* wbig = (__hip_bfloat16*)p; p += (size_t)NWBIG * 2;
    __hip_bfloat16* xzb  = (__hip_bfloat16*)p; p += (size_t)NM * DIN2 * 2;   // 25MB
    __hip_bfloat16* xcb  = (__hip_bfloat16*)p; p += (size_t)NM * DIN * 2;    // 12.6MB
    float*          xbc  = (float*)p;          p += (size_t)NM * 32 * 4;     // 2.1MB
    __hip_bfloat16* dlt  = (__hip_bfloat16*)p; p += (size_t)NM * DIN * 2;    // 12.6MB
    __hip_bfloat16* yb   = (__hip_bfloat16*)p; p += (size_t)NM * DIN * 2;    // 12.6MB
    float*          S    = (float*)p;          p += (size_t)G_CHUNKS * NCH * 4;  // 12.6MB
    float*          Dsum = (float*)p;          p += (size_t)G_CHUNKS * NBD * 4;  // 0.8MB

    // 1. weight conversion + composite dt weight; input transpose+convert
    k_cvt_w<<<dim3((NWI + NWO + NWBIG + 255) / 256), 256, 0, stream>>>(
        W_in, W_out, W_x, W_dt, wbi, wbo, wbig);
    k_cvt_x<<<dim3(L_SEQ/32, DIMC/32, NB), dim3(32, 8), 0, stream>>>(x, xb);
    // 2. in_proj: xzb(m,768) bf16 = xb(m,192) @ wbi(768,192)^T   [K=192: one barrier]
    k_gemm<128, 0><<<dim3(NM/64, DIN2/128), 256, 0, stream>>>(
        xb, wbi, nullptr, xzb, nullptr, nullptr, DIMC, DIN2);
    // 3. depthwise causal conv + silu -> xcb m-major
    k_conv<<<dim3((NM*(size_t)DIN)/256), 256, 0, stream>>>(xzb, conv_w, conv_b, xcb);
    // 4. fused x_proj + dt_proj: xbc(m,32) f32, dlt(m,384) bf16 [BN=64, 7 n-tiles]
    k_gemm<64, 3><<<dim3(NM/64, NBIG/64), 256, 0, stream>>>(
        xcb, wbig, xbc, nullptr, dlt, b_dt, DIN, 0);
    // 5. chunked selective scan (G=128, T=32; Dsum-compressed chunk products)
    k_scan_a<<<dim3(G_CHUNKS, 3, NB), 128, 0, stream>>>(dlt, xcb, xbc, A_log, S, Dsum);
    k_scan_b<<<dim3(NCH/256), 256, 0, stream>>>(S, Dsum, A_log);
    k_scan_c<<<dim3(G_CHUNKS, 3, NB), 128, 0, stream>>>(dlt, xcb, xbc, A_log,
                                                        S, xzb, Dvec, yb);
    // 6. out_proj: out(b,192,l) = yb(m,384) @ wbo(192,384)^T (coalesced epilogue)
    k_gemm<96, 1><<<dim3(NM/64, DIMC/96), 256, 0, stream>>>(
        yb, wbo, out, nullptr, nullptr, nullptr, DIN, 0);
}